// Round 1
// baseline (2087.484 us; speedup 1.0000x reference)
//
#include <hip/hip_runtime.h>
#include <hip/hip_bf16.h>

// TAGConv x2 GNN on MI355X.
// Structure: device-built in-CSR + gather propagation (no hot-loop atomics),
// fp32 tiled vector SGEMM with fused bias/BN/ReLU epilogues.

#define EPS_MSG 1e-7f
#define BNSCALE 0.9999950000374997f  // 1/sqrt(1+1e-5)

// ---------------- CSR build ----------------

__global__ void zero_i32(int* __restrict__ p, int n) {
    int i = blockIdx.x * blockDim.x + threadIdx.x;
    if (i < n) p[i] = 0;
}

__global__ void count_deg(const int* __restrict__ col, int* __restrict__ deg, int E) {
    int e = blockIdx.x * blockDim.x + threadIdx.x;
    if (e < E) atomicAdd(&deg[col[e]], 1);
}

__global__ void compute_dis(const int* __restrict__ deg, float* __restrict__ dis, int N) {
    int v = blockIdx.x * blockDim.x + threadIdx.x;
    if (v < N) dis[v] = (deg[v] > 0) ? rsqrtf((float)deg[v]) : 0.f;
}

// single-block chunked inclusive scan -> exclusive offsets
__global__ void scan_off(const int* __restrict__ deg, int* __restrict__ off, int N) {
    __shared__ int s[1024];
    __shared__ int base;
    if (threadIdx.x == 0) { base = 0; off[0] = 0; }
    __syncthreads();
    for (int b0 = 0; b0 < N; b0 += 1024) {
        int i = b0 + threadIdx.x;
        int d = (i < N) ? deg[i] : 0;
        s[threadIdx.x] = d;
        __syncthreads();
        for (int ofs = 1; ofs < 1024; ofs <<= 1) {
            int t = (threadIdx.x >= ofs) ? s[threadIdx.x - ofs] : 0;
            __syncthreads();
            s[threadIdx.x] += t;
            __syncthreads();
        }
        if (i < N) off[i + 1] = base + s[threadIdx.x];
        __syncthreads();
        if (threadIdx.x == 0) base += s[1023];
        __syncthreads();
    }
}

__global__ void fill_edges(const int* __restrict__ row, const int* __restrict__ col,
                           const float* __restrict__ dis, const int* __restrict__ off,
                           int* __restrict__ cur, int* __restrict__ esrc,
                           float* __restrict__ enorm, int E) {
    int e = blockIdx.x * blockDim.x + threadIdx.x;
    if (e >= E) return;
    int r = row[e], c = col[e];
    int pos = off[c] + atomicAdd(&cur[c], 1);
    esrc[pos] = r;
    enorm[pos] = dis[r] * dis[c];
}

// ---------------- propagation (gather over in-CSR), C=128 ----------------

__global__ void __launch_bounds__(128) prop128(const float* __restrict__ hin,
                                               float* __restrict__ hout,
                                               const int* __restrict__ off,
                                               const int* __restrict__ esrc,
                                               const float* __restrict__ enorm) {
    int v = blockIdx.x;
    int c = threadIdx.x;
    int s = off[v], e = off[v + 1];
    float acc = 0.f;
    for (int i = s; i < e; ++i) {
        float w = enorm[i];
        int src = esrc[i];
        acc += fmaxf(w * hin[src * 128 + c], 0.f);
    }
    hout[v * 128 + c] = acc + (float)(e - s) * EPS_MSG;
}

// ---------------- fp32 SGEMM: C[M,Ntot] (+)= A[M,K] @ B[K,Ntot] ----------------
// epi: 0=none, 1=+bias, 2=bn(relu(bng*((v+bias)*scale)+bnb)), 3=+bias,relu

template <int BN, int TN>
__global__ void __launch_bounds__(256) sgemm_k(
    int M, int Ktot, int Ntot,
    const float* __restrict__ A, const float* __restrict__ B, float* __restrict__ C,
    int beta, int epi,
    const float* __restrict__ bias, const float* __restrict__ bng,
    const float* __restrict__ bnb) {
    constexpr int BM = 128, BK = 16, TM = 8;
    constexpr int TCOLS = BN / TN;   // 16
    constexpr int TROWS = 256 / TCOLS;
    static_assert(TROWS * TM == BM, "tile mismatch");

    __shared__ float As[BK][BM];   // k-major: column reads conflict-free
    __shared__ float Bs[BK][BN];

    int tid = threadIdx.x;
    int tr = tid / TCOLS, tc = tid % TCOLS;
    int m0 = blockIdx.x * BM;
    int n0 = blockIdx.y * BN;

    float acc[TM][TN];
#pragma unroll
    for (int i = 0; i < TM; i++)
#pragma unroll
        for (int j = 0; j < TN; j++) acc[i][j] = 0.f;

    for (int k0 = 0; k0 < Ktot; k0 += BK) {
        // A tile: BM x BK (=2048 floats) via float4, store transposed
#pragma unroll
        for (int it = 0; it < (BM * BK) / (256 * 4); ++it) {
            int f = (tid + it * 256) * 4;
            int r = f / BK;
            int kk = f % BK;
            float4 av = make_float4(0.f, 0.f, 0.f, 0.f);
            int gr = m0 + r;
            if (gr < M) av = *reinterpret_cast<const float4*>(&A[(size_t)gr * Ktot + k0 + kk]);
            As[kk + 0][r] = av.x;
            As[kk + 1][r] = av.y;
            As[kk + 2][r] = av.z;
            As[kk + 3][r] = av.w;
        }
        // B tile: BK x BN
#pragma unroll
        for (int it = 0; it < (BK * BN) / (256 * 4); ++it) {
            int f = (tid + it * 256) * 4;
            int r = f / BN;
            int cc = f % BN;
            *reinterpret_cast<float4*>(&Bs[r][cc]) =
                *reinterpret_cast<const float4*>(&B[(size_t)(k0 + r) * Ntot + n0 + cc]);
        }
        __syncthreads();
#pragma unroll
        for (int kk = 0; kk < BK; ++kk) {
            float a[TM], b[TN];
#pragma unroll
            for (int i = 0; i < TM; i += 4)
                *reinterpret_cast<float4*>(&a[i]) =
                    *reinterpret_cast<const float4*>(&As[kk][tr * TM + i]);
#pragma unroll
            for (int j = 0; j < TN; j += 4)
                *reinterpret_cast<float4*>(&b[j]) =
                    *reinterpret_cast<const float4*>(&Bs[kk][tc * TN + j]);
#pragma unroll
            for (int i = 0; i < TM; i++)
#pragma unroll
                for (int j = 0; j < TN; j++) acc[i][j] = fmaf(a[i], b[j], acc[i][j]);
        }
        __syncthreads();
    }

#pragma unroll
    for (int i = 0; i < TM; i++) {
        int gr = m0 + tr * TM + i;
        if (gr >= M) continue;
#pragma unroll
        for (int j = 0; j < TN; j++) {
            int gc = n0 + tc * TN + j;
            float v = acc[i][j];
            if (beta) v += C[(size_t)gr * Ntot + gc];
            if (epi == 1) {
                v += bias[gc];
            } else if (epi == 2) {
                v = bng[gc] * ((v + bias[gc]) * BNSCALE) + bnb[gc];
                v = fmaxf(v, 0.f);
            } else if (epi == 3) {
                v = fmaxf(v + bias[gc], 0.f);
            }
            C[(size_t)gr * Ntot + gc] = v;
        }
    }
}

extern "C" void kernel_launch(void* const* d_in, const int* in_sizes, int n_in,
                              void* d_out, int out_size, void* d_ws, size_t ws_size,
                              hipStream_t stream) {
    const float* x     = (const float*)d_in[0];
    const int*   ei    = (const int*)d_in[1];
    const float* lins1 = (const float*)d_in[2];
    const float* bias1 = (const float*)d_in[3];
    const float* m1w1  = (const float*)d_in[4];
    const float* m1b1  = (const float*)d_in[5];
    const float* bn1g  = (const float*)d_in[6];
    const float* bn1b  = (const float*)d_in[7];
    const float* m1w2  = (const float*)d_in[8];
    const float* m1b2  = (const float*)d_in[9];
    const float* lins2 = (const float*)d_in[10];
    const float* bias2 = (const float*)d_in[11];
    const float* m2w1  = (const float*)d_in[12];
    const float* m2b1  = (const float*)d_in[13];
    const float* bn2g  = (const float*)d_in[14];
    const float* bn2b  = (const float*)d_in[15];
    const float* m2w2  = (const float*)d_in[16];
    const float* m2b2  = (const float*)d_in[17];
    float* out = (float*)d_out;

    const int N = in_sizes[0] / 128;
    const int E = in_sizes[1] / 2;
    const int* row = ei;
    const int* col = ei + E;

    // workspace carve-up (256B aligned)
    char* ws = (char*)d_ws;
    size_t o = 0;
    auto alloc = [&](size_t bytes) {
        void* p = ws + o;
        o += (bytes + 255) & ~(size_t)255;
        return p;
    };
    int*   deg   = (int*)alloc((size_t)N * 4);
    int*   cur   = (int*)alloc((size_t)N * 4);
    float* dis   = (float*)alloc((size_t)N * 4);
    int*   off   = (int*)alloc((size_t)(N + 1) * 4);
    int*   esrc  = (int*)alloc((size_t)E * 4);
    float* enorm = (float*)alloc((size_t)E * 4);
    const size_t SLOT = (size_t)N * 128;  // floats; N*512 bytes is 256B aligned
    float* S0 = (float*)alloc(SLOT * 4);
    float* S1 = (float*)alloc(SLOT * 4);  // contiguous with S0 -> [N,256] view
    float* S2 = (float*)alloc(SLOT * 4);
    float* S3 = (float*)alloc(SLOT * 4);
    (void)ws_size;

    const int TPB = 256;
    // ---- CSR build ----
    zero_i32<<<(N + TPB - 1) / TPB, TPB, 0, stream>>>(deg, N);
    zero_i32<<<(N + TPB - 1) / TPB, TPB, 0, stream>>>(cur, N);
    count_deg<<<(E + TPB - 1) / TPB, TPB, 0, stream>>>(col, deg, E);
    compute_dis<<<(N + TPB - 1) / TPB, TPB, 0, stream>>>(deg, dis, N);
    scan_off<<<1, 1024, 0, stream>>>(deg, off, N);
    fill_edges<<<(E + TPB - 1) / TPB, TPB, 0, stream>>>(row, col, dis, off, cur, esrc, enorm, E);

    auto gemm128 = [&](const float* A, const float* B, float* C, int M, int K, int Ntot,
                       int beta, int epi, const float* b, const float* g, const float* bb) {
        dim3 grid((M + 127) / 128, Ntot / 128);
        sgemm_k<128, 8><<<grid, 256, 0, stream>>>(M, K, Ntot, A, B, C, beta, epi, b, g, bb);
    };
    auto gemm64 = [&](const float* A, const float* B, float* C, int M, int K, int Ntot,
                      int beta, int epi, const float* b, const float* g, const float* bb) {
        dim3 grid((M + 127) / 128, Ntot / 64);
        sgemm_k<64, 4><<<grid, 256, 0, stream>>>(M, K, Ntot, A, B, C, beta, epi, b, g, bb);
    };

    // ---- Layer 1: TAGConv(128->128) + MLP(128->256->128), then ReLU ----
    // acc1 = S2
    gemm128(x, lins1, S2, N, 128, 128, 0, 0, nullptr, nullptr, nullptr);
    {
        const float* hcur = x;
        float* pp[2] = {S0, S1};
        for (int k = 1; k <= 6; ++k) {
            float* hnxt = pp[(k - 1) & 1];
            prop128<<<N, 128, 0, stream>>>(hcur, hnxt, off, esrc, enorm);
            hcur = hnxt;
            gemm128(hcur, lins1 + (size_t)k * 128 * 128, S2, N, 128, 128, 1,
                    (k == 6) ? 1 : 0, bias1, nullptr, nullptr);
        }
    }
    // z = relu(bn(acc1 @ m1w1 + m1b1))  -> S0:S1 viewed as [N,256]
    gemm128(S2, m1w1, S0, N, 128, 256, 0, 2, m1b1, bn1g, bn1b);
    // h1 = relu(z @ m1w2 + m1b2)        -> S3   (tagconv end + inter-layer relu)
    gemm128(S0, m1w2, S3, N, 256, 128, 0, 3, m1b2, nullptr, nullptr);

    // ---- Layer 2: TAGConv(128->64) + MLP(64->128->64) ----
    // acc2 = S1 (N x 64)
    gemm64(S3, lins2, S1, N, 128, 64, 0, 0, nullptr, nullptr, nullptr);
    {
        const float* hcur = S3;
        for (int k = 1; k <= 6; ++k) {
            float* hnxt = (k & 1) ? S0 : S3;  // S3->S0->S3->...
            prop128<<<N, 128, 0, stream>>>(hcur, hnxt, off, esrc, enorm);
            hcur = hnxt;
            gemm64(hcur, lins2 + (size_t)k * 128 * 64, S1, N, 128, 64, 1,
                   (k == 6) ? 1 : 0, bias2, nullptr, nullptr);
        }
    }
    // z2 = relu(bn(acc2 @ m2w1 + m2b1)) -> S2 (N x 128)
    gemm128(S1, m2w1, S2, N, 64, 128, 0, 2, m2b1, bn2g, bn2b);
    // out = z2 @ m2w2 + m2b2
    gemm64(S2, m2w2, out, N, 128, 64, 0, 1, m2b2, nullptr, nullptr);
}

// Round 2
// 1742.522 us; speedup vs baseline: 1.1980x; 1.1980x over previous
//
#include <hip/hip_runtime.h>
#include <hip/hip_bf16.h>

// TAGConv x2 GNN on MI355X.
// v2: split-bf16 ("PF32") MFMA GEMMs + device CSR + gather propagation.
// PF32 = one uint32 per value: bits[15:0] = bf16(hi), bits[31:16] = bf16(lo),
// value = f(hi) + f(lo), exact to ~2^-18 rel. GEMM: 3 MFMAs (hh, hl, lh).

#define EPS_MSG 1e-7f
#define BNSCALE 0.9999950000374997f  // 1/sqrt(1+1e-5)

typedef __bf16 bf16x8 __attribute__((ext_vector_type(8)));
typedef float f32x4 __attribute__((ext_vector_type(4)));

__device__ __forceinline__ unsigned pack_pf(float f) {
    unsigned u = __float_as_uint(f);
    unsigned hi = (u + 0x7fffu + ((u >> 16) & 1u)) >> 16;  // RNE -> bf16
    float fh = __uint_as_float(hi << 16);
    float r = f - fh;
    unsigned v = __float_as_uint(r);
    unsigned lo = (v + 0x7fffu + ((v >> 16) & 1u)) >> 16;
    return hi | (lo << 16);
}

__device__ __forceinline__ float unpack_pf(unsigned p) {
    return __uint_as_float(p << 16) + __uint_as_float(p & 0xffff0000u);
}

// ---------------- CSR build ----------------

__global__ void zero_i32(int* __restrict__ p, int n) {
    int i = blockIdx.x * blockDim.x + threadIdx.x;
    if (i < n) p[i] = 0;
}

__global__ void count_deg(const int* __restrict__ col, int* __restrict__ deg, int E) {
    int e = blockIdx.x * blockDim.x + threadIdx.x;
    if (e < E) atomicAdd(&deg[col[e]], 1);
}

__global__ void compute_dis(const int* __restrict__ deg, float* __restrict__ dis, int N) {
    int v = blockIdx.x * blockDim.x + threadIdx.x;
    if (v < N) dis[v] = (deg[v] > 0) ? rsqrtf((float)deg[v]) : 0.f;
}

__global__ void scan_off(const int* __restrict__ deg, int* __restrict__ off, int N) {
    __shared__ int s[1024];
    __shared__ int base;
    if (threadIdx.x == 0) { base = 0; off[0] = 0; }
    __syncthreads();
    for (int b0 = 0; b0 < N; b0 += 1024) {
        int i = b0 + threadIdx.x;
        int d = (i < N) ? deg[i] : 0;
        s[threadIdx.x] = d;
        __syncthreads();
        for (int ofs = 1; ofs < 1024; ofs <<= 1) {
            int t = (threadIdx.x >= ofs) ? s[threadIdx.x - ofs] : 0;
            __syncthreads();
            s[threadIdx.x] += t;
            __syncthreads();
        }
        if (i < N) off[i + 1] = base + s[threadIdx.x];
        __syncthreads();
        if (threadIdx.x == 0) base += s[1023];
        __syncthreads();
    }
}

__global__ void fill_edges(const int* __restrict__ row, const int* __restrict__ col,
                           const float* __restrict__ dis, const int* __restrict__ off,
                           int* __restrict__ cur, int* __restrict__ esrc,
                           float* __restrict__ enorm, int E) {
    int e = blockIdx.x * blockDim.x + threadIdx.x;
    if (e >= E) return;
    int r = row[e], c = col[e];
    int pos = off[c] + atomicAdd(&cur[c], 1);
    esrc[pos] = r;
    enorm[pos] = dis[r] * dis[c];
}

// ---------------- conversions ----------------

__global__ void conv_x(const float* __restrict__ in, unsigned* __restrict__ out, int n) {
    int i = blockIdx.x * blockDim.x + threadIdx.x;
    if (i < n) out[i] = pack_pf(in[i]);
}

// out[mat][n][k] = pack(in[mat][k][n])
__global__ void conv_wt(const float* __restrict__ in, unsigned* __restrict__ out,
                        int K, int Nn, int total) {
    int i = blockIdx.x * blockDim.x + threadIdx.x;
    if (i >= total) return;
    int k = i % K;
    int t = i / K;
    int n = t % Nn;
    int mat = t / Nn;
    out[i] = pack_pf(in[(size_t)mat * K * Nn + (size_t)k * Nn + n]);
}

// ---------------- propagation (gather over in-CSR), C=128, PF32 ----------------

__global__ void __launch_bounds__(128) prop_pf(const unsigned* __restrict__ hin,
                                               unsigned* __restrict__ hout,
                                               const int* __restrict__ off,
                                               const int* __restrict__ esrc,
                                               const float* __restrict__ enorm) {
    int v = blockIdx.x;
    int c = threadIdx.x;
    int s = off[v], e = off[v + 1];
    float acc = 0.f;
    for (int i = s; i < e; ++i) {
        float w = enorm[i];
        int src = esrc[i];
        float x = unpack_pf(hin[src * 128 + c]);
        acc += fmaxf(w * x, 0.f);
    }
    hout[v * 128 + c] = pack_pf(acc + (float)(e - s) * EPS_MSG);
}

// ---------------- split-bf16 MFMA GEMM ----------------
// C[M,Ntot] (+)= A[M,Ktot] @ Bt[Ntot,Ktot]^T   (A, Bt in PF32)
// epi: 0=none, 1=+bias, 2=relu(bng*((v+bias)*s)+bnb), 3=relu(v+bias)
// BM=64, BK=32; 128 threads = 2 waves; wave w covers cols [w*BN/2, ...).

template <int BN, int OUTF32>
__global__ __launch_bounds__(128) void gemm_mfma(
    int M, int Ktot, int Ntot,
    const unsigned* __restrict__ A, const unsigned* __restrict__ Bt,
    void* __restrict__ Cp, int beta, int epi,
    const float* __restrict__ bias, const float* __restrict__ bng,
    const float* __restrict__ bnb) {
    constexpr int BM = 64, BK = 32;
    constexpr int WN = BN / 2;    // cols per wave
    constexpr int NF = WN / 16;   // n-fragments per wave
    constexpr int BITERS = BN / 16;

    __shared__ __bf16 Ah[BM][BK], Al[BM][BK];
    __shared__ __bf16 Bh[BN][BK], Bl[BN][BK];

    const int tid = threadIdx.x;
    const int lane = tid & 63;
    const int w = tid >> 6;
    const int m0 = blockIdx.x * BM;
    const int n0 = blockIdx.y * BN;

    uint4 ra[4], rb[BITERS];

    auto stage_load = [&](int k0) {
#pragma unroll
        for (int it = 0; it < 4; ++it) {
            int f = (tid + it * 128) * 4;
            int r = f >> 5, kk = f & 31;
            int gr = m0 + r;
            ra[it] = (gr < M)
                         ? *reinterpret_cast<const uint4*>(&A[(size_t)gr * Ktot + k0 + kk])
                         : make_uint4(0u, 0u, 0u, 0u);
        }
#pragma unroll
        for (int it = 0; it < BITERS; ++it) {
            int f = (tid + it * 128) * 4;
            int r = f >> 5, kk = f & 31;
            rb[it] = *reinterpret_cast<const uint4*>(&Bt[(size_t)(n0 + r) * Ktot + k0 + kk]);
        }
    };

    auto stage_write = [&]() {
#pragma unroll
        for (int it = 0; it < 4; ++it) {
            int f = (tid + it * 128) * 4;
            int r = f >> 5, kk = f & 31;
            uint4 v = ra[it];
            unsigned h01 = (v.x & 0xffffu) | (v.y << 16);
            unsigned h23 = (v.z & 0xffffu) | (v.w << 16);
            unsigned l01 = (v.x >> 16) | (v.y & 0xffff0000u);
            unsigned l23 = (v.z >> 16) | (v.w & 0xffff0000u);
            *reinterpret_cast<uint2*>(&Ah[r][kk]) = make_uint2(h01, h23);
            *reinterpret_cast<uint2*>(&Al[r][kk]) = make_uint2(l01, l23);
        }
#pragma unroll
        for (int it = 0; it < BITERS; ++it) {
            int f = (tid + it * 128) * 4;
            int r = f >> 5, kk = f & 31;
            uint4 v = rb[it];
            unsigned h01 = (v.x & 0xffffu) | (v.y << 16);
            unsigned h23 = (v.z & 0xffffu) | (v.w << 16);
            unsigned l01 = (v.x >> 16) | (v.y & 0xffff0000u);
            unsigned l23 = (v.z >> 16) | (v.w & 0xffff0000u);
            *reinterpret_cast<uint2*>(&Bh[r][kk]) = make_uint2(h01, h23);
            *reinterpret_cast<uint2*>(&Bl[r][kk]) = make_uint2(l01, l23);
        }
    };

    f32x4 acc[4][NF];
#pragma unroll
    for (int fm = 0; fm < 4; ++fm)
#pragma unroll
        for (int fn = 0; fn < NF; ++fn) acc[fm][fn] = (f32x4){0.f, 0.f, 0.f, 0.f};

    stage_load(0);
    const int kiters = Ktot / BK;
    for (int ki = 0; ki < kiters; ++ki) {
        stage_write();
        __syncthreads();
        if (ki + 1 < kiters) stage_load((ki + 1) * BK);

        bf16x8 ah[4], al[4];
#pragma unroll
        for (int fm = 0; fm < 4; ++fm) {
            int rowb = fm * 16 + (lane & 15);
            ah[fm] = *reinterpret_cast<const bf16x8*>(&Ah[rowb][(lane >> 4) * 8]);
            al[fm] = *reinterpret_cast<const bf16x8*>(&Al[rowb][(lane >> 4) * 8]);
        }
#pragma unroll
        for (int fn = 0; fn < NF; ++fn) {
            int colb = w * WN + fn * 16 + (lane & 15);
            bf16x8 bh = *reinterpret_cast<const bf16x8*>(&Bh[colb][(lane >> 4) * 8]);
            bf16x8 bl = *reinterpret_cast<const bf16x8*>(&Bl[colb][(lane >> 4) * 8]);
#pragma unroll
            for (int fm = 0; fm < 4; ++fm) {
                acc[fm][fn] =
                    __builtin_amdgcn_mfma_f32_16x16x32_bf16(ah[fm], bh, acc[fm][fn], 0, 0, 0);
                acc[fm][fn] =
                    __builtin_amdgcn_mfma_f32_16x16x32_bf16(ah[fm], bl, acc[fm][fn], 0, 0, 0);
                acc[fm][fn] =
                    __builtin_amdgcn_mfma_f32_16x16x32_bf16(al[fm], bh, acc[fm][fn], 0, 0, 0);
            }
        }
        __syncthreads();
    }

    // epilogue: C/D layout col = lane&15, row = (lane>>4)*4 + i
#pragma unroll
    for (int fm = 0; fm < 4; ++fm) {
#pragma unroll
        for (int fn = 0; fn < NF; ++fn) {
#pragma unroll
            for (int i = 0; i < 4; ++i) {
                int gr = m0 + fm * 16 + (lane >> 4) * 4 + i;
                if (gr >= M) continue;
                int gc = n0 + w * WN + fn * 16 + (lane & 15);
                float v = acc[fm][fn][i];
                if (beta) v += unpack_pf(((const unsigned*)Cp)[(size_t)gr * Ntot + gc]);
                if (epi == 1) {
                    v += bias[gc];
                } else if (epi == 2) {
                    v = bng[gc] * ((v + bias[gc]) * BNSCALE) + bnb[gc];
                    v = fmaxf(v, 0.f);
                } else if (epi == 3) {
                    v = fmaxf(v + bias[gc], 0.f);
                }
                if (OUTF32)
                    ((float*)Cp)[(size_t)gr * Ntot + gc] = v;
                else
                    ((unsigned*)Cp)[(size_t)gr * Ntot + gc] = pack_pf(v);
            }
        }
    }
}

extern "C" void kernel_launch(void* const* d_in, const int* in_sizes, int n_in,
                              void* d_out, int out_size, void* d_ws, size_t ws_size,
                              hipStream_t stream) {
    const float* x     = (const float*)d_in[0];
    const int*   ei    = (const int*)d_in[1];
    const float* lins1 = (const float*)d_in[2];
    const float* bias1 = (const float*)d_in[3];
    const float* m1w1  = (const float*)d_in[4];
    const float* m1b1  = (const float*)d_in[5];
    const float* bn1g  = (const float*)d_in[6];
    const float* bn1b  = (const float*)d_in[7];
    const float* m1w2  = (const float*)d_in[8];
    const float* m1b2  = (const float*)d_in[9];
    const float* lins2 = (const float*)d_in[10];
    const float* bias2 = (const float*)d_in[11];
    const float* m2w1  = (const float*)d_in[12];
    const float* m2b1  = (const float*)d_in[13];
    const float* bn2g  = (const float*)d_in[14];
    const float* bn2b  = (const float*)d_in[15];
    const float* m2w2  = (const float*)d_in[16];
    const float* m2b2  = (const float*)d_in[17];
    float* out = (float*)d_out;

    const int N = in_sizes[0] / 128;
    const int E = in_sizes[1] / 2;
    const int* row = ei;
    const int* col = ei + E;

    char* ws = (char*)d_ws;
    size_t o = 0;
    auto alloc = [&](size_t bytes) {
        void* p = ws + o;
        o += (bytes + 255) & ~(size_t)255;
        return p;
    };
    int*      deg   = (int*)alloc((size_t)N * 4);
    int*      cur   = (int*)alloc((size_t)N * 4);
    float*    dis   = (float*)alloc((size_t)N * 4);
    int*      off   = (int*)alloc((size_t)(N + 1) * 4);
    int*      esrc  = (int*)alloc((size_t)E * 4);
    float*    enorm = (float*)alloc((size_t)E * 4);
    const size_t SLOT = (size_t)N * 128;  // uints (N*512 bytes, 256B aligned)
    unsigned* X   = (unsigned*)alloc(SLOT * 4);
    unsigned* P0  = (unsigned*)alloc(SLOT * 4);
    unsigned* P1  = (unsigned*)alloc(SLOT * 4);
    unsigned* ACC = (unsigned*)alloc(SLOT * 4);
    unsigned* Wt1  = (unsigned*)alloc((size_t)7 * 128 * 128 * 4);
    unsigned* Wt2  = (unsigned*)alloc((size_t)7 * 64 * 128 * 4);
    unsigned* Wm1a = (unsigned*)alloc((size_t)256 * 128 * 4);
    unsigned* Wm1b = (unsigned*)alloc((size_t)128 * 256 * 4);
    unsigned* Wm2a = (unsigned*)alloc((size_t)128 * 64 * 4);
    unsigned* Wm2b = (unsigned*)alloc((size_t)64 * 128 * 4);
    (void)ws_size;

    // aliases (lifetimes disjoint; X,P0,P1,ACC are contiguous slots)
    unsigned* Z    = X;    // [N,256] over X..P0
    unsigned* H1   = P1;   // [N,128]
    unsigned* ACC2 = ACC;  // [N,64]
    unsigned* L2A  = X;    // layer-2 ping
    unsigned* L2B  = P0;   // layer-2 pong
    unsigned* Z2   = X;    // [N,128]

    const int TPB = 256;
    zero_i32<<<(N + TPB - 1) / TPB, TPB, 0, stream>>>(deg, N);
    zero_i32<<<(N + TPB - 1) / TPB, TPB, 0, stream>>>(cur, N);
    count_deg<<<(E + TPB - 1) / TPB, TPB, 0, stream>>>(col, deg, E);
    compute_dis<<<(N + TPB - 1) / TPB, TPB, 0, stream>>>(deg, dis, N);
    scan_off<<<1, 1024, 0, stream>>>(deg, off, N);
    fill_edges<<<(E + TPB - 1) / TPB, TPB, 0, stream>>>(row, col, dis, off, cur, esrc, enorm, E);

    conv_x<<<(N * 128 + TPB - 1) / TPB, TPB, 0, stream>>>(x, X, N * 128);
    {
        int t1 = 7 * 128 * 128;
        conv_wt<<<(t1 + TPB - 1) / TPB, TPB, 0, stream>>>(lins1, Wt1, 128, 128, t1);
        int t2 = 7 * 64 * 128;
        conv_wt<<<(t2 + TPB - 1) / TPB, TPB, 0, stream>>>(lins2, Wt2, 128, 64, t2);
        int t3 = 256 * 128;
        conv_wt<<<(t3 + TPB - 1) / TPB, TPB, 0, stream>>>(m1w1, Wm1a, 128, 256, t3);
        conv_wt<<<(t3 + TPB - 1) / TPB, TPB, 0, stream>>>(m1w2, Wm1b, 256, 128, t3);
        int t4 = 128 * 64;
        conv_wt<<<(t4 + TPB - 1) / TPB, TPB, 0, stream>>>(m2w1, Wm2a, 64, 128, t4);
        conv_wt<<<(t4 + TPB - 1) / TPB, TPB, 0, stream>>>(m2w2, Wm2b, 128, 64, t4);
    }

    auto g128 = [&](const unsigned* A, const unsigned* Bt, void* C, int Ktot, int Ntot,
                    int beta, int epi, const float* b, const float* g, const float* bb) {
        dim3 grid((N + 63) / 64, Ntot / 128);
        gemm_mfma<128, 0><<<grid, 128, 0, stream>>>(N, Ktot, Ntot, A, Bt, C, beta, epi, b, g, bb);
    };
    auto g64 = [&](const unsigned* A, const unsigned* Bt, void* C, int Ktot,
                   int beta, int epi, const float* b) {
        dim3 grid((N + 63) / 64, 1);
        gemm_mfma<64, 0><<<grid, 128, 0, stream>>>(N, Ktot, 64, A, Bt, C, beta, epi, b, nullptr,
                                                   nullptr);
    };

    // ---- Layer 1: TAGConv(128->128) ----
    g128(X, Wt1, ACC, 128, 128, 0, 0, nullptr, nullptr, nullptr);
    {
        const unsigned* hcur = X;
        unsigned* pp[2] = {P0, P1};
        for (int k = 1; k <= 6; ++k) {
            unsigned* hnxt = pp[(k - 1) & 1];
            prop_pf<<<N, 128, 0, stream>>>(hcur, hnxt, off, esrc, enorm);
            hcur = hnxt;
            g128(hcur, Wt1 + (size_t)k * 128 * 128, ACC, 128, 128, 1, (k == 6) ? 1 : 0, bias1,
                 nullptr, nullptr);
        }
    }
    // MLP1: z = relu(bn(acc@m1w1+m1b1)); h1 = relu(z@m1w2+m1b2)
    g128(ACC, Wm1a, Z, 128, 256, 0, 2, m1b1, bn1g, bn1b);
    g128(Z, Wm1b, H1, 256, 128, 0, 3, m1b2, nullptr, nullptr);

    // ---- Layer 2: TAGConv(128->64) ----
    g64(H1, Wt2, ACC2, 128, 0, 0, nullptr);
    {
        const unsigned* hcur = H1;
        for (int k = 1; k <= 6; ++k) {
            unsigned* hnxt = (k & 1) ? L2A : L2B;
            prop_pf<<<N, 128, 0, stream>>>(hcur, hnxt, off, esrc, enorm);
            hcur = hnxt;
            g64(hcur, Wt2 + (size_t)k * 64 * 128, ACC2, 128, 1, (k == 6) ? 1 : 0, bias2);
        }
    }
    // MLP2: z2 = relu(bn(acc2@m2w1+m2b1)); out = z2@m2w2+m2b2 (fp32)
    {
        dim3 grid((N + 63) / 64, 1);
        gemm_mfma<128, 0><<<grid, 128, 0, stream>>>(N, 64, 128, ACC2, Wm2a, Z2, 0, 2, m2b1, bn2g,
                                                    bn2b);
        gemm_mfma<64, 1><<<grid, 128, 0, stream>>>(N, 128, 64, Z2, Wm2b, out, 0, 1, m2b2, nullptr,
                                                   nullptr);
    }
}

// Round 3
// 1039.606 us; speedup vs baseline: 2.0080x; 1.6761x over previous
//
#include <hip/hip_runtime.h>
#include <hip/hip_bf16.h>

// TAGConv x2 GNN on MI355X. v3:
//  - linear-prop transform: g = dis*relu(h); h_new = dis*sum(g[src]) + deg*EPS
//    (relu(norm*x) == norm*relu(x) for norm>=0; h_k>=0 for k>=1)
//  - gather unrolled x4 (4 outstanding loads/wave, latency-bound fix)
//  - concat-K GEMM: all 7 hop features stored as [N][896], one GEMM per layer
//  - PF32 storage everywhere: u32 = (bf16 hi | bf16 lo<<16), 3-MFMA split GEMM

#define EPS_MSG 1e-7f
#define BNSCALE 0.9999950000374997f  // 1/sqrt(1+1e-5)

typedef __bf16 bf16x8 __attribute__((ext_vector_type(8)));
typedef float f32x4 __attribute__((ext_vector_type(4)));

__device__ __forceinline__ unsigned pack_pf(float f) {
    unsigned u = __float_as_uint(f);
    unsigned hi = (u + 0x7fffu + ((u >> 16) & 1u)) >> 16;  // RNE -> bf16
    float fh = __uint_as_float(hi << 16);
    float r = f - fh;
    unsigned v = __float_as_uint(r);
    unsigned lo = (v + 0x7fffu + ((v >> 16) & 1u)) >> 16;
    return hi | (lo << 16);
}
__device__ __forceinline__ float unpack_pf(unsigned p) {
    return __uint_as_float(p << 16) + __uint_as_float(p & 0xffff0000u);
}

// ---------------- CSR build ----------------

__global__ void zero_i32(int* __restrict__ p, int n) {
    int i = blockIdx.x * blockDim.x + threadIdx.x;
    if (i < n) p[i] = 0;
}

__global__ void count_deg(const int* __restrict__ col, int* __restrict__ deg, int E) {
    int e = blockIdx.x * blockDim.x + threadIdx.x;
    if (e < E) atomicAdd(&deg[col[e]], 1);
}

__global__ void compute_dis(const int* __restrict__ deg, float* __restrict__ dis, int N) {
    int v = blockIdx.x * blockDim.x + threadIdx.x;
    if (v < N) dis[v] = (deg[v] > 0) ? rsqrtf((float)deg[v]) : 0.f;
}

__global__ void scan_blk(const int* __restrict__ deg, int* __restrict__ off,
                         int* __restrict__ bsum, int N) {
    __shared__ int s[1024];
    int i = blockIdx.x * 1024 + threadIdx.x;
    s[threadIdx.x] = (i < N) ? deg[i] : 0;
    __syncthreads();
    for (int ofs = 1; ofs < 1024; ofs <<= 1) {
        int t = (threadIdx.x >= (unsigned)ofs) ? s[threadIdx.x - ofs] : 0;
        __syncthreads();
        s[threadIdx.x] += t;
        __syncthreads();
    }
    if (i < N) off[i + 1] = s[threadIdx.x];
    if (threadIdx.x == 0) bsum[blockIdx.x] = s[1023];
}

__global__ void scan_top(int* __restrict__ bsum, int nb) {
    if (threadIdx.x == 0 && blockIdx.x == 0) {
        int a = 0;
        for (int b = 0; b < nb; ++b) {
            int t = bsum[b];
            bsum[b] = a;
            a += t;
        }
    }
}

__global__ void scan_add(int* __restrict__ off, const int* __restrict__ bsum, int N) {
    int i = blockIdx.x * 1024 + threadIdx.x;
    if (i < N) off[i + 1] += bsum[blockIdx.x];
    if (i == 0) off[0] = 0;
}

__global__ void fill_edges(const int* __restrict__ row, const int* __restrict__ col,
                           const int* __restrict__ off, int* __restrict__ cur,
                           int* __restrict__ esrc, int E) {
    int e = blockIdx.x * blockDim.x + threadIdx.x;
    if (e >= E) return;
    int c = col[e];
    int pos = off[c] + atomicAdd(&cur[c], 1);
    esrc[pos] = row[e];
}

// ---------------- conversions ----------------

// h0 = pack(x) (strided), g0 = pack(dis*relu(x))
__global__ void conv_xg(const float* __restrict__ x, unsigned* __restrict__ h, int hs,
                        unsigned* __restrict__ g, const float* __restrict__ dis, int total) {
    int i = blockIdx.x * blockDim.x + threadIdx.x;
    if (i >= total) return;
    int v = i >> 7, c = i & 127;
    float xv = x[i];
    h[(size_t)v * hs + c] = pack_pf(xv);
    g[i] = pack_pf(dis[v] * fmaxf(xv, 0.f));
}

// out[n][km*K + k] = pack(in[km][k][n])  (concatenated-K, B^T layout)
__global__ void conv_wt(const float* __restrict__ in, unsigned* __restrict__ out,
                        int nmats, int K, int Nn) {
    int total = nmats * K * Nn;
    int i = blockIdx.x * blockDim.x + threadIdx.x;
    if (i >= total) return;
    int KT = nmats * K;
    int n = i / KT;
    int rem = i - n * KT;
    int km = rem / K, k = rem - km * K;
    out[i] = pack_pf(in[(size_t)km * K * Nn + (size_t)k * Nn + n]);
}

// ---------------- propagation: h[v] = dis[v]*sum(g[src]) + deg*EPS ----------------

template <int WRITEG>
__global__ void __launch_bounds__(128) prop(const unsigned* __restrict__ gin,
                                            unsigned* __restrict__ hout, int hstride,
                                            unsigned* __restrict__ gout,
                                            const float* __restrict__ dis,
                                            const int* __restrict__ off,
                                            const int* __restrict__ esrc) {
    int v = blockIdx.x;
    int c = threadIdx.x;
    int s = off[v], e = off[v + 1];
    float a0 = 0.f, a1 = 0.f, a2 = 0.f, a3 = 0.f;
    int i = s;
    for (; i + 4 <= e; i += 4) {
        int s0 = esrc[i], s1 = esrc[i + 1], s2 = esrc[i + 2], s3 = esrc[i + 3];
        unsigned p0 = gin[(size_t)s0 * 128 + c];
        unsigned p1 = gin[(size_t)s1 * 128 + c];
        unsigned p2 = gin[(size_t)s2 * 128 + c];
        unsigned p3 = gin[(size_t)s3 * 128 + c];
        a0 += unpack_pf(p0);
        a1 += unpack_pf(p1);
        a2 += unpack_pf(p2);
        a3 += unpack_pf(p3);
    }
    for (; i < e; ++i) a0 += unpack_pf(gin[(size_t)esrc[i] * 128 + c]);
    float dv = dis[v];
    float h = dv * ((a0 + a1) + (a2 + a3)) + (float)(e - s) * EPS_MSG;
    hout[(size_t)v * hstride + c] = pack_pf(h);
    if (WRITEG) gout[(size_t)v * 128 + c] = pack_pf(dv * h);
}

// ---------------- split-bf16 MFMA GEMM ----------------
// C[M,Ntot](ldc) (+)= A[M,Ktot] @ Bt[Ntot][ldb]^T ; A,Bt PF32.
// epi: 0=none 1=+bias 2=relu(bn) 3=relu(+bias); optional gout=pack(dis*v).

template <int BN, int OUTF32>
__global__ __launch_bounds__(256) void gemm3(
    int M, int Ktot, int Ntot, int ldc, int ldb,
    const unsigned* __restrict__ A, const unsigned* __restrict__ Bt, void* __restrict__ Cp,
    int beta, int epi, const float* __restrict__ bias, const float* __restrict__ bng,
    const float* __restrict__ bnb, unsigned* __restrict__ gout,
    const float* __restrict__ dis) {
    constexpr int BM = 64, BK = 32, PAD = 40;
    constexpr int WC = (BN == 128) ? 2 : 1;  // waves along N
    constexpr int WR = 4 / WC;               // waves along M
    constexpr int WROWS = BM / WR;           // 32 or 16
    constexpr int WCOLS = BN / WC;           // 64
    constexpr int MF = WROWS / 16;
    constexpr int NF = WCOLS / 16;
    constexpr int AIT = (BM * BK) / (256 * 4);
    constexpr int BIT = (BN * BK) / (256 * 4);

    __shared__ __bf16 Ah[BM][PAD], Al[BM][PAD], Bh[BN][PAD], Bl[BN][PAD];

    const int tid = threadIdx.x;
    const int lane = tid & 63;
    const int w = tid >> 6;
    const int wr = w / WC, wc = w % WC;
    const int m0 = blockIdx.x * BM;
    const int n0 = blockIdx.y * BN;

    uint4 ra[AIT], rb[BIT];

    auto stage_load = [&](int k0) {
#pragma unroll
        for (int it = 0; it < AIT; ++it) {
            int f = (tid + it * 256) * 4;
            int r = f >> 5, kk = f & 31;
            int gr = m0 + r;
            ra[it] = (gr < M)
                         ? *reinterpret_cast<const uint4*>(&A[(size_t)gr * Ktot + k0 + kk])
                         : make_uint4(0u, 0u, 0u, 0u);
        }
#pragma unroll
        for (int it = 0; it < BIT; ++it) {
            int f = (tid + it * 256) * 4;
            int r = f >> 5, kk = f & 31;
            rb[it] = *reinterpret_cast<const uint4*>(&Bt[(size_t)(n0 + r) * ldb + k0 + kk]);
        }
    };
    auto split_store = [&](uint4 v, __bf16* ph, __bf16* pl) {
        unsigned h01 = (v.x & 0xffffu) | (v.y << 16);
        unsigned h23 = (v.z & 0xffffu) | (v.w << 16);
        unsigned l01 = (v.x >> 16) | (v.y & 0xffff0000u);
        unsigned l23 = (v.z >> 16) | (v.w & 0xffff0000u);
        *reinterpret_cast<uint2*>(ph) = make_uint2(h01, h23);
        *reinterpret_cast<uint2*>(pl) = make_uint2(l01, l23);
    };
    auto stage_write = [&]() {
#pragma unroll
        for (int it = 0; it < AIT; ++it) {
            int f = (tid + it * 256) * 4;
            int r = f >> 5, kk = f & 31;
            split_store(ra[it], &Ah[r][kk], &Al[r][kk]);
        }
#pragma unroll
        for (int it = 0; it < BIT; ++it) {
            int f = (tid + it * 256) * 4;
            int r = f >> 5, kk = f & 31;
            split_store(rb[it], &Bh[r][kk], &Bl[r][kk]);
        }
    };

    f32x4 acc[MF][NF];
#pragma unroll
    for (int fm = 0; fm < MF; ++fm)
#pragma unroll
        for (int fn = 0; fn < NF; ++fn) acc[fm][fn] = (f32x4){0.f, 0.f, 0.f, 0.f};

    stage_load(0);
    const int kiters = Ktot / BK;
    for (int ki = 0; ki < kiters; ++ki) {
        stage_write();
        __syncthreads();
        if (ki + 1 < kiters) stage_load((ki + 1) * BK);

        const int koff = (lane >> 4) * 8;
        bf16x8 ah[MF], al[MF];
#pragma unroll
        for (int fm = 0; fm < MF; ++fm) {
            int rowb = wr * WROWS + fm * 16 + (lane & 15);
            ah[fm] = *reinterpret_cast<const bf16x8*>(&Ah[rowb][koff]);
            al[fm] = *reinterpret_cast<const bf16x8*>(&Al[rowb][koff]);
        }
#pragma unroll
        for (int fn = 0; fn < NF; ++fn) {
            int colb = wc * WCOLS + fn * 16 + (lane & 15);
            bf16x8 bh = *reinterpret_cast<const bf16x8*>(&Bh[colb][koff]);
            bf16x8 bl = *reinterpret_cast<const bf16x8*>(&Bl[colb][koff]);
#pragma unroll
            for (int fm = 0; fm < MF; ++fm) {
                acc[fm][fn] =
                    __builtin_amdgcn_mfma_f32_16x16x32_bf16(ah[fm], bh, acc[fm][fn], 0, 0, 0);
                acc[fm][fn] =
                    __builtin_amdgcn_mfma_f32_16x16x32_bf16(ah[fm], bl, acc[fm][fn], 0, 0, 0);
                acc[fm][fn] =
                    __builtin_amdgcn_mfma_f32_16x16x32_bf16(al[fm], bh, acc[fm][fn], 0, 0, 0);
            }
        }
        __syncthreads();
    }

    // C/D layout: col = lane&15, row = (lane>>4)*4 + i
#pragma unroll
    for (int fm = 0; fm < MF; ++fm) {
#pragma unroll
        for (int fn = 0; fn < NF; ++fn) {
#pragma unroll
            for (int i = 0; i < 4; ++i) {
                int gr = m0 + wr * WROWS + fm * 16 + (lane >> 4) * 4 + i;
                if (gr >= M) continue;
                int gc = n0 + wc * WCOLS + fn * 16 + (lane & 15);
                float v = acc[fm][fn][i];
                if (beta) v += unpack_pf(((const unsigned*)Cp)[(size_t)gr * ldc + gc]);
                if (epi == 1) {
                    v += bias[gc];
                } else if (epi == 2) {
                    v = bng[gc] * ((v + bias[gc]) * BNSCALE) + bnb[gc];
                    v = fmaxf(v, 0.f);
                } else if (epi == 3) {
                    v = fmaxf(v + bias[gc], 0.f);
                }
                if (OUTF32)
                    ((float*)Cp)[(size_t)gr * ldc + gc] = v;
                else
                    ((unsigned*)Cp)[(size_t)gr * ldc + gc] = pack_pf(v);
                if (gout) gout[(size_t)gr * 128 + gc] = pack_pf(dis[gr] * v);
            }
        }
    }
}

extern "C" void kernel_launch(void* const* d_in, const int* in_sizes, int n_in,
                              void* d_out, int out_size, void* d_ws, size_t ws_size,
                              hipStream_t stream) {
    const float* x     = (const float*)d_in[0];
    const int*   ei    = (const int*)d_in[1];
    const float* lins1 = (const float*)d_in[2];
    const float* bias1 = (const float*)d_in[3];
    const float* m1w1  = (const float*)d_in[4];
    const float* m1b1  = (const float*)d_in[5];
    const float* bn1g  = (const float*)d_in[6];
    const float* bn1b  = (const float*)d_in[7];
    const float* m1w2  = (const float*)d_in[8];
    const float* m1b2  = (const float*)d_in[9];
    const float* lins2 = (const float*)d_in[10];
    const float* bias2 = (const float*)d_in[11];
    const float* m2w1  = (const float*)d_in[12];
    const float* m2b1  = (const float*)d_in[13];
    const float* bn2g  = (const float*)d_in[14];
    const float* bn2b  = (const float*)d_in[15];
    const float* m2w2  = (const float*)d_in[16];
    const float* m2b2  = (const float*)d_in[17];
    float* out = (float*)d_out;

    const int N = in_sizes[0] / 128;
    const int E = in_sizes[1] / 2;
    const int* row = ei;
    const int* col = ei + E;

    char* ws = (char*)d_ws;
    size_t o = 0;
    auto alloc = [&](size_t bytes) {
        void* p = ws + o;
        o += (bytes + 255) & ~(size_t)255;
        return p;
    };
    int*      deg  = (int*)alloc((size_t)N * 4);
    int*      cur  = (int*)alloc((size_t)N * 4);
    float*    dis  = (float*)alloc((size_t)N * 4);
    int*      off  = (int*)alloc((size_t)(N + 1) * 4);
    int*      bsum = (int*)alloc(256 * 4);
    int*      esrc = (int*)alloc((size_t)E * 4);
    unsigned* gA   = (unsigned*)alloc((size_t)N * 128 * 4);  // N*512 bytes: 256-aligned,
    unsigned* gB   = (unsigned*)alloc((size_t)N * 128 * 4);  // gB is contiguous after gA
    unsigned* ACC  = (unsigned*)alloc((size_t)N * 128 * 4);
    unsigned* Wc1  = (unsigned*)alloc((size_t)128 * 896 * 4);
    unsigned* Wc2  = (unsigned*)alloc((size_t)64 * 896 * 4);
    unsigned* Wm1a = (unsigned*)alloc((size_t)256 * 128 * 4);
    unsigned* Wm1b = (unsigned*)alloc((size_t)128 * 256 * 4);
    unsigned* Wm2a = (unsigned*)alloc((size_t)128 * 64 * 4);
    unsigned* Wm2b = (unsigned*)alloc((size_t)64 * 128 * 4);
    unsigned* H = (unsigned*)(ws + o);  // big path: [N][896]; FB: [N][128]
    const size_t need_big = o + (size_t)N * 896 * 4;
    const bool big = (ws_size >= need_big);
    const int HS = big ? 896 : 128;
    unsigned* Z  = gA;  // [N,256] spans gA..gB
    unsigned* Z2 = gA;  // [N,128] (late phase)
    unsigned* ACC2 = gB;  // [N,64]  (late phase)

    const int TPB = 256;
    const int nb = (N + 1023) / 1024;
    zero_i32<<<(N + TPB - 1) / TPB, TPB, 0, stream>>>(deg, N);
    zero_i32<<<(N + TPB - 1) / TPB, TPB, 0, stream>>>(cur, N);
    count_deg<<<(E + TPB - 1) / TPB, TPB, 0, stream>>>(col, deg, E);
    compute_dis<<<(N + TPB - 1) / TPB, TPB, 0, stream>>>(deg, dis, N);
    scan_blk<<<nb, 1024, 0, stream>>>(deg, off, bsum, N);
    scan_top<<<1, 64, 0, stream>>>(bsum, nb);
    scan_add<<<nb, 1024, 0, stream>>>(off, bsum, N);
    fill_edges<<<(E + TPB - 1) / TPB, TPB, 0, stream>>>(row, col, off, cur, esrc, E);

    conv_wt<<<(7 * 128 * 128 + TPB - 1) / TPB, TPB, 0, stream>>>(lins1, Wc1, 7, 128, 128);
    conv_wt<<<(7 * 128 * 64 + TPB - 1) / TPB, TPB, 0, stream>>>(lins2, Wc2, 7, 128, 64);
    conv_wt<<<(128 * 256 + TPB - 1) / TPB, TPB, 0, stream>>>(m1w1, Wm1a, 1, 128, 256);
    conv_wt<<<(256 * 128 + TPB - 1) / TPB, TPB, 0, stream>>>(m1w2, Wm1b, 1, 256, 128);
    conv_wt<<<(64 * 128 + TPB - 1) / TPB, TPB, 0, stream>>>(m2w1, Wm2a, 1, 64, 128);
    conv_wt<<<(128 * 64 + TPB - 1) / TPB, TPB, 0, stream>>>(m2w2, Wm2b, 1, 128, 64);

    conv_xg<<<(N * 128 + TPB - 1) / TPB, TPB, 0, stream>>>(x, H, HS, gA, dis, N * 128);

    const int HG = (N + 63) / 64;
    auto g128 = [&](const unsigned* A, int Ktot, const unsigned* Bt, int ldb, void* C, int ldc,
                    int Ntot, int beta, int epi, const float* b, const float* g,
                    const float* bb, unsigned* gout) {
        dim3 grid(HG, Ntot / 128);
        gemm3<128, 0><<<grid, 256, 0, stream>>>(N, Ktot, Ntot, ldc, ldb, A, Bt, C, beta, epi, b,
                                                g, bb, gout, dis);
    };
    auto g64 = [&](const unsigned* A, int Ktot, const unsigned* Bt, int ldb, void* C, int ldc,
                   int beta, int epi, const float* b, int outf32) {
        dim3 grid(HG, 1);
        if (outf32)
            gemm3<64, 1><<<grid, 256, 0, stream>>>(N, Ktot, 64, ldc, ldb, A, Bt, C, beta, epi, b,
                                                   nullptr, nullptr, nullptr, nullptr);
        else
            gemm3<64, 0><<<grid, 256, 0, stream>>>(N, Ktot, 64, ldc, ldb, A, Bt, C, beta, epi, b,
                                                   nullptr, nullptr, nullptr, nullptr);
    };

    // ---- Layer 1 TAGConv ----
    if (big) {
        unsigned* gp[2] = {gA, gB};
        for (int k = 1; k <= 6; ++k) {
            const unsigned* gin = gp[(k - 1) & 1];
            unsigned* gout = gp[k & 1];
            if (k < 6)
                prop<1><<<N, 128, 0, stream>>>(gin, H + k * 128, 896, gout, dis, off, esrc);
            else
                prop<0><<<N, 128, 0, stream>>>(gin, H + k * 128, 896, nullptr, dis, off, esrc);
        }
        g128(H, 896, Wc1, 896, ACC, 128, 128, 0, 1, bias1, nullptr, nullptr, nullptr);
    } else {
        g128(H, 128, Wc1 + 0, 896, ACC, 128, 128, 0, 0, nullptr, nullptr, nullptr, nullptr);
        unsigned* gp[2] = {gA, gB};
        for (int k = 1; k <= 6; ++k) {
            const unsigned* gin = gp[(k - 1) & 1];
            unsigned* gout = gp[k & 1];
            if (k < 6)
                prop<1><<<N, 128, 0, stream>>>(gin, H, 128, gout, dis, off, esrc);
            else
                prop<0><<<N, 128, 0, stream>>>(gin, H, 128, nullptr, dis, off, esrc);
            g128(H, 128, Wc1 + k * 128, 896, ACC, 128, 128, 1, (k == 6) ? 1 : 0, bias1, nullptr,
                 nullptr, nullptr);
        }
    }
    // ---- MLP1 + inter-layer relu; h1 -> H slot0, g0(L2)=pack(dis*h1) -> ACC ----
    g128(ACC, 128, Wm1a, 128, Z, 256, 256, 0, 2, m1b1, bn1g, bn1b, nullptr);
    g128(Z, 256, Wm1b, 256, H, HS, 128, 0, 3, m1b2, nullptr, nullptr, ACC);

    // ---- Layer 2 TAGConv ----
    if (big) {
        const unsigned* gin = ACC;
        unsigned* gp[2] = {gA, gB};
        for (int k = 1; k <= 6; ++k) {
            unsigned* gout = gp[(k - 1) & 1];
            if (k < 6)
                prop<1><<<N, 128, 0, stream>>>(gin, H + k * 128, 896, gout, dis, off, esrc);
            else
                prop<0><<<N, 128, 0, stream>>>(gin, H + k * 128, 896, nullptr, dis, off, esrc);
            gin = gout;
        }
        g64(H, 896, Wc2, 896, ACC2, 64, 0, 1, bias2, 0);
    } else {
        g64(H, 128, Wc2 + 0, 896, ACC2, 64, 0, 0, nullptr, 0);
        const unsigned* gin = ACC;
        unsigned* gp[2] = {gA, ACC};
        for (int k = 1; k <= 6; ++k) {
            unsigned* gout = gp[(k - 1) & 1];  // gA, ACC, gA, ...
            if (k < 6)
                prop<1><<<N, 128, 0, stream>>>(gin, H, 128, gout, dis, off, esrc);
            else
                prop<0><<<N, 128, 0, stream>>>(gin, H, 128, nullptr, dis, off, esrc);
            gin = gout;
            g64(H, 128, Wc2 + k * 128, 896, ACC2, 64, 1, (k == 6) ? 1 : 0, bias2, 0);
        }
    }
    // ---- MLP2 ----
    g128(ACC2, 64, Wm2a, 64, Z2, 128, 128, 0, 2, m2b1, bn2g, bn2b, nullptr);
    g64(Z2, 128, Wm2b, 128, out, 64, 0, 1, m2b2, 1);
}